// Round 7
// baseline (46.319 us; speedup 1.0000x reference)
//
#include <hip/hip_runtime.h>
#include <math.h>

// ---- compile-time problem constants (from setup_inputs) ----
#define B_SZ 2
#define HI 48
#define WI 48
#define NG (HI*WI)          // 2304 gaussians per image
#define NT (B_SZ*NG)        // 4608 total gaussians
#define HIDN 256
#define HT 96
#define WT 96
#define PT (HT*WT)          // 9216 pixels per image
#define FACTOR 2.0f         // max(96/48, 96/48)
#define OFF_SCALE 0.125f    // 3 * (2*factor / max(Ht,Wt))
#define A_MIN (1.0f/255.0f)
#define A_MAX 0.99f
#define LN255 5.54126354516f   // ln(255): w >= 1/255 <=> sigma <= LN255

#define GPB 8               // gaussians per block in MLP kernel (8 | 48 -> same row)
#define RTS 8               // render tile size (8x8 px, 1 wave per block)

// ws layout: ga[NT] f4 (px,py,conA,conB) | gb[NT] f4 (conC,r,g,b)
//          | gt[NT] f4 (px,py,rx,ry)     | gfeat[NT*64] float

// ---- wave64 sum via DPP (VALU pipe, no LDS). Result valid in lane 63. ----
__device__ __forceinline__ float wave_sum(float v) {
#define DPP_ADD(CTRL) \
    v += __int_as_float(__builtin_amdgcn_update_dpp(0, __float_as_int(v), CTRL, 0xF, 0xF, true))
    DPP_ADD(0x111);   // row_shr:1
    DPP_ADD(0x112);   // row_shr:2
    DPP_ADD(0x114);   // row_shr:4
    DPP_ADD(0x118);   // row_shr:8  -> lane 15 of each row16 = row sum
    DPP_ADD(0x142);   // row_bcast:15 -> lane31 = row0+1, lane63 = row2+3
    DPP_ADD(0x143);   // row_bcast:31 -> lane63 = total
#undef DPP_ADD
    return v;
}

// ---- kernel A: conv3x3 SAME, weights in VGPRs (lane = out channel) ----
__global__ __launch_bounds__(256) void conv_kernel(
    const float* __restrict__ inp, const float* __restrict__ enc_w,
    const float* __restrict__ enc_b, float* __restrict__ gfeat)
{
    const int t  = threadIdx.x;
    const int o  = t & 63;
    const int wv = t >> 6;                     // wave 0..3
    float w[27];
    #pragma unroll
    for (int j = 0; j < 27; ++j) w[j] = enc_w[o*27 + j];
    const float bias = enc_b[o];

    const int p0 = blockIdx.x * 16 + wv * 4;   // 4 pixels per wave
    #pragma unroll
    for (int i = 0; i < 4; ++i) {
        int n = p0 + i;
        int b = n / NG, pix = n % NG;
        int y = pix / WI, x = pix % WI;
        const float* __restrict__ ip = inp + (size_t)b*3*HI*WI;
        float acc = bias;
        if (y >= 1 && y <= HI-2 && x >= 1 && x <= WI-2) {   // interior (wave-uniform)
            #pragma unroll
            for (int c = 0; c < 3; ++c)
                #pragma unroll
                for (int ky = 0; ky < 3; ++ky)
                    #pragma unroll
                    for (int kx = 0; kx < 3; ++kx)
                        acc += w[c*9 + ky*3 + kx] * ip[(c*HI + y+ky-1)*WI + x+kx-1];
        } else {
            #pragma unroll
            for (int c = 0; c < 3; ++c)
                #pragma unroll
                for (int ky = 0; ky < 3; ++ky) {
                    int yy = y + ky - 1;
                    #pragma unroll
                    for (int kx = 0; kx < 3; ++kx) {
                        int xx = x + kx - 1;
                        float v = ((unsigned)yy < HI && (unsigned)xx < WI)
                                  ? ip[(c*HI + yy)*WI + xx] : 0.f;
                        acc += w[c*9 + ky*3 + kx] * v;
                    }
                }
        }
        gfeat[(size_t)n*64 + o] = acc;         // coalesced
    }
}

// ---- layer-2 for one MLP (one wave): register partials + DPP reduce ----
#define L2_BRANCH(W2P, B2P, OD, OBASE)                                        \
  {                                                                           \
    float wv2[4*OD];                                                          \
    _Pragma("unroll")                                                         \
    for (int q = 0; q < OD; ++q)                                              \
      *(float4*)&wv2[q*4] = *(const float4*)&W2P[h0*OD + q*4];                \
    _Pragma("unroll")                                                         \
    for (int j = 0; j < OD; ++j) {                                            \
      float b2v = B2P[j];                                                     \
      _Pragma("unroll")                                                       \
      for (int gi = 0; gi < GPB; ++gi) {                                      \
        float s = acc[0][gi]*wv2[0*OD+j] + acc[1][gi]*wv2[1*OD+j]             \
                + acc[2][gi]*wv2[2*OD+j] + acc[3][gi]*wv2[3*OD+j];            \
        s = wave_sum(s);                                                      \
        if ((t & 63) == 63) outv[gi][OBASE + j] = s + b2v;                    \
      }                                                                       \
    }                                                                         \
  }

// ---- kernel B: 4 MLPs (wave = MLP), layer-1 reg tile, layer-2 DPP ----
__global__ __launch_bounds__(256, 4) void mlp_kernel(
    const float* __restrict__ gfeat,
    const float* __restrict__ ow1, const float* __restrict__ ob1, const float* __restrict__ ow2, const float* __restrict__ ob2,
    const float* __restrict__ sw1, const float* __restrict__ sb1, const float* __restrict__ sw2, const float* __restrict__ sb2,
    const float* __restrict__ rw1, const float* __restrict__ rb1, const float* __restrict__ rw2, const float* __restrict__ rb2,
    const float* __restrict__ cw1, const float* __restrict__ cb1, const float* __restrict__ cw2, const float* __restrict__ cb2,
    float4* __restrict__ ga, float4* __restrict__ gb, float4* __restrict__ gt)
{
    __shared__ __align__(16) float feat[GPB][68];   // staged conv output
    __shared__ float outv[GPB][8];

    const int t  = threadIdx.x;
    const int n0 = blockIdx.x * GPB;
    const int pix0 = n0 % NG;
    const int y  = pix0 / WI;
    const int x0 = pix0 % WI;

    // stage feat[8][64] from global (coalesced float4)
    if (t < 128) {
        int gi = t >> 4, q = t & 15;
        *(float4*)&feat[gi][q*4] = ((const float4*)gfeat)[(size_t)(n0 + gi)*16 + q];
    }
    __syncthreads();

    // ---- layer 1: thread = (mlp m, h-quad); 4 h x 8 gi register tile ----
    const int m  = t >> 6;          // wave-uniform
    const int h0 = (t & 63) * 4;
    float acc[4][GPB];
    {
        const float* __restrict__ w1 = (m == 0) ? ow1 : (m == 1) ? sw1 : (m == 2) ? rw1 : cw1;
        const float* __restrict__ b1 = (m == 0) ? ob1 : (m == 1) ? sb1 : (m == 2) ? rb1 : cb1;
        #pragma unroll
        for (int hh = 0; hh < 4; ++hh)
            #pragma unroll
            for (int gi = 0; gi < GPB; ++gi) acc[hh][gi] = 0.f;

        #pragma unroll 4
        for (int it = 0; it < 16; ++it) {           // k = it*4 .. it*4+3
            float4 w0  = *(const float4*)&w1[(it*4 + 0)*HIDN + h0];
            float4 w1v = *(const float4*)&w1[(it*4 + 1)*HIDN + h0];
            float4 w2v = *(const float4*)&w1[(it*4 + 2)*HIDN + h0];
            float4 w3v = *(const float4*)&w1[(it*4 + 3)*HIDN + h0];
            #pragma unroll
            for (int gi = 0; gi < GPB; ++gi) {
                float4 f = *(const float4*)&feat[gi][it*4];
                acc[0][gi] += f.x*w0.x + f.y*w1v.x + f.z*w2v.x + f.w*w3v.x;
                acc[1][gi] += f.x*w0.y + f.y*w1v.y + f.z*w2v.y + f.w*w3v.y;
                acc[2][gi] += f.x*w0.z + f.y*w1v.z + f.z*w2v.z + f.w*w3v.z;
                acc[3][gi] += f.x*w0.w + f.y*w1v.w + f.z*w2v.w + f.w*w3v.w;
            }
        }
        // effective bias: b1 + FACTOR * w1[k=64 row]
        float4 bb = *(const float4*)&b1[h0];
        float4 wl = *(const float4*)&w1[64*HIDN + h0];
        bb.x += FACTOR * wl.x; bb.y += FACTOR * wl.y;
        bb.z += FACTOR * wl.z; bb.w += FACTOR * wl.w;
        #pragma unroll
        for (int gi = 0; gi < GPB; ++gi) {
            acc[0][gi] = fmaxf(acc[0][gi] + bb.x, 0.f);
            acc[1][gi] = fmaxf(acc[1][gi] + bb.y, 0.f);
            acc[2][gi] = fmaxf(acc[2][gi] + bb.z, 0.f);
            acc[3][gi] = fmaxf(acc[3][gi] + bb.w, 0.f);
        }
    }

    // ---- layer 2: register partials + DPP wave reduce (VALU pipe) ----
    if (m == 0)      L2_BRANCH(ow2, ob2, 2, 0)
    else if (m == 1) L2_BRANCH(sw2, sb2, 2, 2)
    else if (m == 2) L2_BRANCH(rw2, rb2, 1, 4)
    else             L2_BRANCH(cw2, cb2, 3, 5)
    __syncthreads();

    // ---- activations + projection + conic + cull radii ----
    if (t < GPB) {
        int gi = t, n = n0 + gi;
        int x = x0 + gi;
        float cy = -1.f + (2.f*y + 1.f) / (float)HI;
        float cx = -1.f + (2.f*x + 1.f) / (float)WI;
        float xyy = cy + tanhf(outv[gi][0]) * OFF_SCALE;
        float xyx = cx + tanhf(outv[gi][1]) * OFF_SCALE;
        float pxp = (xyx + 1.f) * 0.5f * (float)WT - 0.5f;
        float pyp = (xyy + 1.f) * 0.5f * (float)HT - 0.5f;
        float t2 = outv[gi][2], t3 = outv[gi][3];
        float s0 = (t2 > 0.f ? t2 : expf(t2) - 1.f) + 1.5f;
        float s1 = (t3 > 0.f ? t3 : expf(t3) - 1.f) + 1.5f;
        float rot = tanhf(outv[gi][4]) * 3.14159265358979323846f;
        float cr = cosf(rot), sr = sinf(rot);
        float sx2 = s0*s0, sy2 = s1*s1;
        float cov_a = cr*cr*sx2 + sr*sr*sy2;
        float cov_b = cr*sr*(sx2 - sy2);
        float cov_c = sr*sr*sx2 + cr*cr*sy2;
        float det = cov_a*cov_c - cov_b*cov_b;
        float conA = cov_c / det, conB = -cov_b / det, conC = cov_a / det;
        float c0 = 1.f/(1.f + expf(-outv[gi][5]));
        float c1 = 1.f/(1.f + expf(-outv[gi][6]));
        float c2 = 1.f/(1.f + expf(-outv[gi][7]));
        float rx = sqrtf(2.f * LN255 * cov_a);
        float ry = sqrtf(2.f * LN255 * cov_c);
        ga[n] = make_float4(pxp, pyp, conA, conB);
        gb[n] = make_float4(conC, c0, c1, c2);
        gt[n] = make_float4(pxp, pyp, rx, ry);
    }
}

// ---- kernel C: render, 1 wave per 8x8 tile, ballot compaction, no atomics ----
__global__ __launch_bounds__(64) void render_kernel(
    const float4* __restrict__ ga, const float4* __restrict__ gb,
    const float4* __restrict__ gt, float* __restrict__ out)
{
    __shared__ unsigned short sidx[NG];
    __shared__ __align__(16) float4 lp0[64];
    __shared__ __align__(16) float4 lp1[64];

    const int t    = threadIdx.x;             // 0..63 (one wave)
    const int b    = blockIdx.y;
    const int tile = blockIdx.x;              // 0..143
    const int tx   = (tile % (WT/RTS)) * RTS;
    const int ty   = (tile / (WT/RTS)) * RTS;
    const float cx = tx + (RTS-1)*0.5f;
    const float cy = ty + (RTS-1)*0.5f;
    const float hw = (RTS-1)*0.5f;
    const unsigned long long lmask = (1ull << t) - 1ull;

    // phase 1: bbox cull + wave compaction (deterministic lane order)
    int cnt = 0;
    #pragma unroll 4
    for (int i = 0; i < NG/64; ++i) {         // 36 iterations
        int n = i*64 + t;
        float4 v = gt[b*NG + n];              // px, py, rx, ry  (coalesced)
        bool keep = (fabsf(v.x - cx) <= v.z + hw) && (fabsf(v.y - cy) <= v.w + hw);
        unsigned long long mask = __ballot(keep);
        if (keep) sidx[cnt + __popcll(mask & lmask)] = (unsigned short)n;
        cnt += __popcll(mask);
    }

    // phase 2: chunks of 64 staged to LDS (same wave: no barrier needed)
    const float gxf = (float)(tx + (t & (RTS-1)));
    const float gyf = (float)(ty + (t >> 3));
    float ra = 0.f, gg = 0.f, ba = 0.f, aa = 0.f;
    for (int base = 0; base < cnt; base += 64) {
        int cn = min(64, cnt - base);
        if (t < cn) {
            int n = b*NG + sidx[base + t];
            lp0[t] = ga[n];                   // px, py, conA, conB
            lp1[t] = gb[n];                   // conC, r, g, b
        }
        #pragma unroll 4
        for (int j = 0; j < cn; ++j) {
            float4 c0 = lp0[j];
            float4 c1 = lp1[j];
            float dx = gxf - c0.x, dy = gyf - c0.y;
            float sg = 0.5f*(c0.z*dx*dx + c1.x*dy*dy) + c0.w*(dx*dy);
            float w = __expf(-sg);
            float alpha = (sg >= 0.f && w >= A_MIN) ? fminf(w, A_MAX) : 0.f;
            ra += alpha * c1.y;
            gg += alpha * c1.z;
            ba += alpha * c1.w;
            aa += alpha;
        }
    }

    float T = fminf(fmaxf(1.f - aa, 0.f), 1.f);
    int o = (b*PT + (ty + (t >> 3))*WT + tx + (t & (RTS-1))) * 3;
    out[o + 0] = ra + T;
    out[o + 1] = gg + T;
    out[o + 2] = ba + T;
}

extern "C" void kernel_launch(void* const* d_in, const int* in_sizes, int n_in,
                              void* d_out, int out_size, void* d_ws, size_t ws_size,
                              hipStream_t stream)
{
    const float* inp   = (const float*)d_in[0];
    const float* enc_w = (const float*)d_in[1];
    const float* enc_b = (const float*)d_in[2];
    const float* ow1 = (const float*)d_in[3];
    const float* ob1 = (const float*)d_in[4];
    const float* ow2 = (const float*)d_in[5];
    const float* ob2 = (const float*)d_in[6];
    const float* sw1 = (const float*)d_in[7];
    const float* sb1 = (const float*)d_in[8];
    const float* sw2 = (const float*)d_in[9];
    const float* sb2 = (const float*)d_in[10];
    const float* rw1 = (const float*)d_in[11];
    const float* rb1 = (const float*)d_in[12];
    const float* rw2 = (const float*)d_in[13];
    const float* rb2 = (const float*)d_in[14];
    const float* cw1 = (const float*)d_in[15];
    const float* cb1 = (const float*)d_in[16];
    const float* cw2 = (const float*)d_in[17];
    const float* cb2 = (const float*)d_in[18];

    float4* ga    = (float4*)d_ws;            // NT float4
    float4* gb    = ga + NT;                  // NT float4
    float4* gt    = gb + NT;                  // NT float4
    float*  gfeat = (float*)(gt + NT);        // NT*64 floats

    conv_kernel<<<NT/16, 256, 0, stream>>>(inp, enc_w, enc_b, gfeat);
    mlp_kernel<<<NT/GPB, 256, 0, stream>>>(gfeat,
                                           ow1, ob1, ow2, ob2,
                                           sw1, sb1, sw2, sb2,
                                           rw1, rb1, rw2, rb2,
                                           cw1, cb1, cw2, cb2,
                                           ga, gb, gt);
    render_kernel<<<dim3((WT/RTS)*(HT/RTS), B_SZ), 64, 0, stream>>>(ga, gb, gt, (float*)d_out);
}

// Round 8
// 34.582 us; speedup vs baseline: 1.3394x; 1.3394x over previous
//
#include <hip/hip_runtime.h>
#include <math.h>

// ---- compile-time problem constants (from setup_inputs) ----
#define B_SZ 2
#define HI 48
#define WI 48
#define NG (HI*WI)          // 2304 gaussians per image
#define NT (B_SZ*NG)        // 4608 total gaussians
#define HIDN 256
#define HT 96
#define WT 96
#define PT (HT*WT)          // 9216 pixels per image
#define FACTOR 2.0f         // max(96/48, 96/48)
#define OFF_SCALE 0.125f    // 3 * (2*factor / max(Ht,Wt))
#define A_MIN (1.0f/255.0f)
#define A_MAX 0.99f
#define LN255 5.54126354516f   // ln(255): w >= 1/255 <=> sigma <= LN255

#define GPB 8               // gaussians per block in param kernel (8 | 48 -> same row)
#define TS 16               // render tile size (16x16 px)

// ws layout: ga[NT] f4 (px,py,conA,conB) | gb[NT] f4 (conC,r,g,b) | gt[NT] f4 (px,py,rx,ry)

__global__ __launch_bounds__(256, 3) void param_kernel(
    const float* __restrict__ inp, const float* __restrict__ enc_w, const float* __restrict__ enc_b,
    const float* __restrict__ ow1, const float* __restrict__ ob1, const float* __restrict__ ow2, const float* __restrict__ ob2,
    const float* __restrict__ sw1, const float* __restrict__ sb1, const float* __restrict__ sw2, const float* __restrict__ sb2,
    const float* __restrict__ rw1, const float* __restrict__ rb1, const float* __restrict__ rw2, const float* __restrict__ rb2,
    const float* __restrict__ cw1, const float* __restrict__ cb1, const float* __restrict__ cw2, const float* __restrict__ cb2,
    float4* __restrict__ ga, float4* __restrict__ gb, float4* __restrict__ gt)
{
    __shared__ float sinp[3][3][12];                 // input patch: 3ch x 3 rows x 10 cols (pad 12)
    __shared__ float swt[64*27];                     // conv weights
    __shared__ __align__(16) float feat[GPB][68];    // conv output, float4-readable
    __shared__ __align__(16) float hid[4][GPB][260]; // layer-1 output, stride 260
    __shared__ __align__(16) float w2t[8][260];      // transposed layer-2 weights: w2t[o][k]
    __shared__ float red[256];
    __shared__ float outv[GPB][8];

    const int t  = threadIdx.x;
    const int n0 = blockIdx.x * GPB;
    const int b  = n0 / NG;
    const int pix0 = n0 % NG;
    const int y  = pix0 / WI;
    const int x0 = pix0 % WI;     // block's 8 pixels: (y, x0..x0+7), same row

    // ---- stage conv weights + input patch + transposed w2 to LDS ----
    for (int i = t; i < 64*27; i += 256) swt[i] = enc_w[i];
    if (t < 90) {
        int c = t / 30, r = (t / 10) % 3, cc = t % 10;
        int yy = y + r - 1;
        int xx = x0 + cc - 1;
        float v = 0.f;
        if (yy >= 0 && yy < HI && xx >= 0 && xx < WI)
            v = inp[((b*3 + c)*HI + yy)*WI + xx];
        sinp[c][r][cc] = v;
    }
    for (int i = t; i < 2048; i += 256) {
        int o = i >> 8, k = i & 255;
        float v;
        if (o < 2)      v = ow2[k*2 + o];
        else if (o < 4) v = sw2[k*2 + (o-2)];
        else if (o < 5) v = rw2[k];
        else            v = cw2[k*3 + (o-5)];
        w2t[o][k] = v;
    }
    __syncthreads();

    // ---- conv 3x3 SAME (64 out ch) x 8 gaussians: 512 tasks over 256 threads ----
    for (int rep = 0; rep < 2; ++rep) {
        int idx = rep * 256 + t;
        int gi = idx >> 6, o = idx & 63;
        float acc = enc_b[o];
        #pragma unroll
        for (int c = 0; c < 3; ++c)
            #pragma unroll
            for (int ky = 0; ky < 3; ++ky)
                #pragma unroll
                for (int kx = 0; kx < 3; ++kx)
                    acc += swt[o*27 + c*9 + ky*3 + kx] * sinp[c][ky][gi + kx];
        feat[gi][o] = acc;
    }
    __syncthreads();

    // ---- layer 1: thread = (mlp m, h-quad); software-pipelined weight loads ----
    const int m  = t >> 6;          // wave-uniform
    const int h0 = (t & 63) * 4;
    {
        const float* __restrict__ w1 = (m == 0) ? ow1 : (m == 1) ? sw1 : (m == 2) ? rw1 : cw1;
        const float* __restrict__ b1 = (m == 0) ? ob1 : (m == 1) ? sb1 : (m == 2) ? rb1 : cb1;
        float acc[4][GPB];
        #pragma unroll
        for (int hh = 0; hh < 4; ++hh)
            #pragma unroll
            for (int gi = 0; gi < GPB; ++gi) acc[hh][gi] = 0.f;

        // prefetch group 0
        float4 wA0 = *(const float4*)&w1[0*HIDN + h0];
        float4 wA1 = *(const float4*)&w1[1*HIDN + h0];
        float4 wA2 = *(const float4*)&w1[2*HIDN + h0];
        float4 wA3 = *(const float4*)&w1[3*HIDN + h0];

        for (int it = 0; it < 15; ++it) {           // groups 0..14, prefetch it+1
            float4 wB0 = *(const float4*)&w1[(it*4 + 4)*HIDN + h0];
            float4 wB1 = *(const float4*)&w1[(it*4 + 5)*HIDN + h0];
            float4 wB2 = *(const float4*)&w1[(it*4 + 6)*HIDN + h0];
            float4 wB3 = *(const float4*)&w1[(it*4 + 7)*HIDN + h0];
            #pragma unroll
            for (int gi = 0; gi < GPB; ++gi) {
                float4 f = *(const float4*)&feat[gi][it*4];
                acc[0][gi] += f.x*wA0.x + f.y*wA1.x + f.z*wA2.x + f.w*wA3.x;
                acc[1][gi] += f.x*wA0.y + f.y*wA1.y + f.z*wA2.y + f.w*wA3.y;
                acc[2][gi] += f.x*wA0.z + f.y*wA1.z + f.z*wA2.z + f.w*wA3.z;
                acc[3][gi] += f.x*wA0.w + f.y*wA1.w + f.z*wA2.w + f.w*wA3.w;
            }
            wA0 = wB0; wA1 = wB1; wA2 = wB2; wA3 = wB3;
        }
        // peeled group 15 (k = 60..63)
        #pragma unroll
        for (int gi = 0; gi < GPB; ++gi) {
            float4 f = *(const float4*)&feat[gi][60];
            acc[0][gi] += f.x*wA0.x + f.y*wA1.x + f.z*wA2.x + f.w*wA3.x;
            acc[1][gi] += f.x*wA0.y + f.y*wA1.y + f.z*wA2.y + f.w*wA3.y;
            acc[2][gi] += f.x*wA0.z + f.y*wA1.z + f.z*wA2.z + f.w*wA3.z;
            acc[3][gi] += f.x*wA0.w + f.y*wA1.w + f.z*wA2.w + f.w*wA3.w;
        }

        // effective bias: b1 + FACTOR * w1[k=64 row]  (feat[64] == FACTOR const)
        float4 bb = *(const float4*)&b1[h0];
        float4 wl = *(const float4*)&w1[64*HIDN + h0];
        bb.x += FACTOR * wl.x; bb.y += FACTOR * wl.y;
        bb.z += FACTOR * wl.z; bb.w += FACTOR * wl.w;
        #pragma unroll
        for (int gi = 0; gi < GPB; ++gi) {
            float4 hv;
            hv.x = fmaxf(acc[0][gi] + bb.x, 0.f);
            hv.y = fmaxf(acc[1][gi] + bb.y, 0.f);
            hv.z = fmaxf(acc[2][gi] + bb.z, 0.f);
            hv.w = fmaxf(acc[3][gi] + bb.w, 0.f);
            *(float4*)&hid[m][gi][h0] = hv;
        }
    }
    __syncthreads();

    // ---- layer 2: 64 (gi,o) dot-256, 4-way k split, all b128 LDS reads ----
    {
        int o = t & 7, gi = (t >> 3) & 7, q = t >> 6;   // q in 0..3
        int mm = (o < 2) ? 0 : (o < 4) ? 1 : (o < 5) ? 2 : 3;
        float p = 0.f;
        int k0 = q * 64;
        #pragma unroll
        for (int kk = 0; kk < 16; ++kk) {
            float4 hv = *(const float4*)&hid[mm][gi][k0 + kk*4];
            float4 wv = *(const float4*)&w2t[o][k0 + kk*4];
            p += hv.x*wv.x + hv.y*wv.y + hv.z*wv.z + hv.w*wv.w;
        }
        red[t] = p;
    }
    __syncthreads();
    if (t < 64) {
        int o = t & 7;
        float v = red[t] + red[t+64] + red[t+128] + red[t+192];
        float b2 = (o < 2) ? ob2[o] : (o < 4) ? sb2[o-2] : (o < 5) ? rb2[0] : cb2[o-5];
        outv[t >> 3][o] = v + b2;
    }
    __syncthreads();

    // ---- activations + projection + conic + cull radii ----
    if (t < GPB) {
        int gi = t, n = n0 + gi;
        int x = x0 + gi;
        float cy = -1.f + (2.f*y + 1.f) / (float)HI;
        float cx = -1.f + (2.f*x + 1.f) / (float)WI;
        float xyy = cy + tanhf(outv[gi][0]) * OFF_SCALE;
        float xyx = cx + tanhf(outv[gi][1]) * OFF_SCALE;
        float pxp = (xyx + 1.f) * 0.5f * (float)WT - 0.5f;
        float pyp = (xyy + 1.f) * 0.5f * (float)HT - 0.5f;
        float t2 = outv[gi][2], t3 = outv[gi][3];
        float s0 = (t2 > 0.f ? t2 : expf(t2) - 1.f) + 1.5f;
        float s1 = (t3 > 0.f ? t3 : expf(t3) - 1.f) + 1.5f;
        float rot = tanhf(outv[gi][4]) * 3.14159265358979323846f;
        float cr = cosf(rot), sr = sinf(rot);
        float sx2 = s0*s0, sy2 = s1*s1;
        float cov_a = cr*cr*sx2 + sr*sr*sy2;
        float cov_b = cr*sr*(sx2 - sy2);
        float cov_c = sr*sr*sx2 + cr*cr*sy2;
        float det = cov_a*cov_c - cov_b*cov_b;
        float conA = cov_c / det, conB = -cov_b / det, conC = cov_a / det;
        float c0 = 1.f/(1.f + expf(-outv[gi][5]));
        float c1 = 1.f/(1.f + expf(-outv[gi][6]));
        float c2 = 1.f/(1.f + expf(-outv[gi][7]));
        float rx = sqrtf(2.f * LN255 * cov_a);
        float ry = sqrtf(2.f * LN255 * cov_c);
        ga[n] = make_float4(pxp, pyp, conA, conB);
        gb[n] = make_float4(conC, c0, c1, c2);
        gt[n] = make_float4(pxp, pyp, rx, ry);
    }
}

// ---- render: 1024 threads = 256 pixels x 4 survivor slices ----
__global__ __launch_bounds__(1024) void render_kernel(
    const float4* __restrict__ ga, const float4* __restrict__ gb,
    const float4* __restrict__ gt, float* __restrict__ out)
{
    __shared__ unsigned short sidx[NG];
    __shared__ int ns;
    __shared__ __align__(16) float4 lp0[256];
    __shared__ __align__(16) float4 lp1[256];
    __shared__ __align__(16) float4 sred[3][256];   // slices 1..3 partials

    const int t    = threadIdx.x;
    const int q    = t >> 8;                  // survivor slice 0..3 (wave-uniform)
    const int p    = t & 255;                 // pixel within tile
    const int b    = blockIdx.y;
    const int tile = blockIdx.x;              // 0..35
    const int tx   = (tile % (WT/TS)) * TS;
    const int ty   = (tile / (WT/TS)) * TS;
    const float cx = tx + (TS-1)*0.5f;
    const float cy = ty + (TS-1)*0.5f;
    const float hw = (TS-1)*0.5f;

    if (t == 0) ns = 0;
    __syncthreads();

    // ---- phase 1: conservative bbox test, compact survivor indices ----
    for (int n = t; n < NG; n += 1024) {
        float4 v = gt[b*NG + n];              // px, py, rx, ry
        if (fabsf(v.x - cx) <= v.z + hw && fabsf(v.y - cy) <= v.w + hw) {
            int slot = atomicAdd(&ns, 1);
            sidx[slot] = (unsigned short)n;
        }
    }
    __syncthreads();
    const int total = ns;

    const float gxf = (float)(tx + (p & (TS-1)));
    const float gyf = (float)(ty + (p / TS));
    float ra = 0.f, gg = 0.f, ba = 0.f, aa = 0.f;

    // ---- phase 2: chunks of 256 staged to LDS; each slice q walks j = q (mod 4) ----
    for (int base = 0; base < total; base += 256) {
        int cn = min(256, total - base);
        __syncthreads();
        if (t < cn) {
            int n = b*NG + sidx[base + t];
            lp0[t] = ga[n];                   // px, py, conA, conB
            lp1[t] = gb[n];                   // conC, r, g, b
        }
        __syncthreads();
        for (int j = q; j < cn; j += 4) {
            float4 c0 = lp0[j];
            float4 c1 = lp1[j];
            float dx = gxf - c0.x, dy = gyf - c0.y;
            float sg = 0.5f*(c0.z*dx*dx + c1.x*dy*dy) + c0.w*(dx*dy);
            float w = __expf(-sg);
            float alpha = (sg >= 0.f && w >= A_MIN) ? fminf(w, A_MAX) : 0.f;
            ra += alpha * c1.y;
            gg += alpha * c1.z;
            ba += alpha * c1.w;
            aa += alpha;
        }
    }

    // ---- combine the 4 slices ----
    if (q > 0) sred[q-1][p] = make_float4(ra, gg, ba, aa);
    __syncthreads();
    if (q == 0) {
        #pragma unroll
        for (int s = 0; s < 3; ++s) {
            float4 v = sred[s][p];
            ra += v.x; gg += v.y; ba += v.z; aa += v.w;
        }
        float T = fminf(fmaxf(1.f - aa, 0.f), 1.f);
        int o = (b*PT + (ty + p/TS)*WT + tx + (p & (TS-1))) * 3;
        out[o + 0] = ra + T;
        out[o + 1] = gg + T;
        out[o + 2] = ba + T;
    }
}

extern "C" void kernel_launch(void* const* d_in, const int* in_sizes, int n_in,
                              void* d_out, int out_size, void* d_ws, size_t ws_size,
                              hipStream_t stream)
{
    const float* inp   = (const float*)d_in[0];
    const float* enc_w = (const float*)d_in[1];
    const float* enc_b = (const float*)d_in[2];
    const float* ow1 = (const float*)d_in[3];
    const float* ob1 = (const float*)d_in[4];
    const float* ow2 = (const float*)d_in[5];
    const float* ob2 = (const float*)d_in[6];
    const float* sw1 = (const float*)d_in[7];
    const float* sb1 = (const float*)d_in[8];
    const float* sw2 = (const float*)d_in[9];
    const float* sb2 = (const float*)d_in[10];
    const float* rw1 = (const float*)d_in[11];
    const float* rb1 = (const float*)d_in[12];
    const float* rw2 = (const float*)d_in[13];
    const float* rb2 = (const float*)d_in[14];
    const float* cw1 = (const float*)d_in[15];
    const float* cb1 = (const float*)d_in[16];
    const float* cw2 = (const float*)d_in[17];
    const float* cb2 = (const float*)d_in[18];

    float4* ga = (float4*)d_ws;            // NT float4
    float4* gb = ga + NT;                  // NT float4
    float4* gt = gb + NT;                  // NT float4

    param_kernel<<<NT/GPB, 256, 0, stream>>>(inp, enc_w, enc_b,
                                             ow1, ob1, ow2, ob2,
                                             sw1, sb1, sw2, sb2,
                                             rw1, rb1, rw2, rb2,
                                             cw1, cb1, cw2, cb2,
                                             ga, gb, gt);
    render_kernel<<<dim3((WT/TS)*(HT/TS), B_SZ), 1024, 0, stream>>>(ga, gb, gt, (float*)d_out);
}